// Round 7
// baseline (418.021 us; speedup 1.0000x reference)
//
#include <hip/hip_runtime.h>

#define USER_COUNT 200000
#define ITEM_COUNT 100000
#define N_NODES    300000   // USER_COUNT + ITEM_COUNT
#define EMB        64
#define BATCH      4096

typedef unsigned int   u32;
typedef unsigned short u16;
typedef u16   ushort8v __attribute__((ext_vector_type(8)));
typedef float float8v  __attribute__((ext_vector_type(8)));
typedef int   int2v    __attribute__((ext_vector_type(2)));

static __device__ __forceinline__ float bf2f(u16 h) {
    return __uint_as_float(((u32)h) << 16);
}
static __device__ __forceinline__ u16 f2bf(float f) {   // round-to-nearest-even
    u32 u = __float_as_uint(f);
    u32 r = (u + 0x7FFFu + ((u >> 16) & 1u)) >> 16;
    return (u16)r;
}

// ---------------------------------------------------------------------------
// row_ptr from sorted COO rows. ptr[r] = first i with row[i] >= r.
// ---------------------------------------------------------------------------
__global__ void build_row_ptr(const int* __restrict__ row,
                              int* __restrict__ ptr, int nnz) {
    int i = blockIdx.x * blockDim.x + threadIdx.x;
    if (i >= nnz) return;
    int r  = row[i];
    int rp = (i == 0) ? -1 : row[i - 1];
    for (int rr = rp + 1; rr <= r; ++rr) ptr[rr] = i;
    if (i == nnz - 1) {
        for (int rr = r + 1; rr <= N_NODES; ++rr) ptr[rr] = nnz;
    }
}

// ---------------------------------------------------------------------------
// cv[i] = {col[i], bits(val[i])} : one 8B record per edge (one dwordx2 load
// in the SpMM instead of two dword loads from separate streams).
// ---------------------------------------------------------------------------
__global__ void build_cv(const int* __restrict__ col,
                         const float* __restrict__ val,
                         int2v* __restrict__ cv, int nnz) {
    int i = blockIdx.x * blockDim.x + threadIdx.x;
    if (i >= nnz) return;
    int2v t;
    t.x = col[i];
    t.y = __float_as_int(val[i]);
    __builtin_nontemporal_store(t, cv + i);
}

// ---------------------------------------------------------------------------
// ego16 = bf16(concat(user_emb, item_emb)); each thread converts 4 elems.
// ---------------------------------------------------------------------------
__global__ void convert_bf16(const float* __restrict__ ue,
                             const float* __restrict__ ie,
                             u16* __restrict__ out16) {
    size_t t = (size_t)blockIdx.x * blockDim.x + threadIdx.x;
    const size_t total = (size_t)N_NODES * EMB / 4;
    if (t >= total) return;
    size_t base = t * 4;
    const size_t ub = (size_t)USER_COUNT * EMB;
    const float* src = (base < ub) ? (ue + base) : (ie + (base - ub));
    float4 v = *(const float4*)src;
    ushort4 o;
    o.x = f2bf(v.x); o.y = f2bf(v.y); o.z = f2bf(v.z); o.w = f2bf(v.w);
    *(ushort4*)(out16 + base) = o;
}

// ---------------------------------------------------------------------------
// Mark nodes whose h2 row is actually consumed.
// ---------------------------------------------------------------------------
__global__ void mark_needed(const int* __restrict__ users,
                            const int* __restrict__ items,
                            const int* __restrict__ col,
                            const int* __restrict__ ptr,
                            u32* __restrict__ flag) {
    int slot = (int)((blockIdx.x * blockDim.x + threadIdx.x) >> 6);
    if (slot >= 2 * BATCH) return;
    int lane = threadIdx.x & 63;
    int row = (slot < BATCH) ? users[slot] : (items[slot - BATCH] + USER_COUNT);
    if (lane == 0) flag[row] = 1;
    int p0 = ptr[row];
    int p1 = ptr[row + 1];
    for (int j = p0 + lane; j < p1; j += 64) flag[col[j]] = 1;
}

// ---------------------------------------------------------------------------
// Edge loaders (cv-interleaved or separate col/val streams).
// ---------------------------------------------------------------------------
template <bool USE_CV>
static __device__ __forceinline__ void load_edge(
        const int2v* __restrict__ cv, const int* __restrict__ col,
        const float* __restrict__ val, int j, int& c, float& v) {
    if (USE_CV) {
        int2v t = __builtin_nontemporal_load(cv + j);
        c = t.x; v = __int_as_float(t.y);
    } else {
        c = __builtin_nontemporal_load(col + j);
        v = __builtin_nontemporal_load(val + j);
    }
}

// clean step: no predication (only valid when the full 16-edge tile is in range)
template <bool USE_CV>
static __device__ __forceinline__ void edge_clean(
        const u16* __restrict__ x, const int2v* cv, const int* col,
        const float* val, int j, int d, float8v& acc) {
    int c; float v;
    load_edge<USE_CV>(cv, col, val, j, c, v);
    ushort8v h8 = *(const ushort8v*)(x + (size_t)c * EMB + d);
    float8v xf;
    #pragma unroll
    for (int q = 0; q < 8; ++q) xf[q] = bf2f(h8[q]);
    acc += v * xf;
}

// predicated step: clamp index into segment, zero the weight if out of range
template <bool USE_CV>
static __device__ __forceinline__ void edge_pred(
        const u16* __restrict__ x, const int2v* cv, const int* col,
        const float* val, int jj, int p1, int p1m1, int d, float8v& acc) {
    int jc = (jj < p1) ? jj : p1m1;
    int c; float v;
    load_edge<USE_CV>(cv, col, val, jc, c, v);
    v = (jj < p1) ? v : 0.0f;
    ushort8v h8 = *(const ushort8v*)(x + (size_t)c * EMB + d);
    float8v xf;
    #pragma unroll
    for (int q = 0; q < 8; ++q) xf[q] = bf2f(h8[q]);
    acc += v * xf;
}

#define SLOT_REDUCE(ACC)                                              \
    _Pragma("unroll")                                                 \
    for (int q = 0; q < 8; ++q) {                                     \
        ACC[q] += __shfl_xor(ACC[q], 8, 64);                          \
        ACC[q] += __shfl_xor(ACC[q], 16, 64);                         \
        ACC[q] += __shfl_xor(ACC[q], 32, 64);                         \
    }

// ---------------------------------------------------------------------------
// Full SpMM (bf16 in / bf16 out): one wave per row.
//   e = lane>>3 : edge slot (8 concurrent edges); d = (lane&7)*8 dims.
// Clean main loop (full 16-edge tiles, no predication) + one predicated
// epilogue tile. Wave-uniform trip counts -> zero divergence.
// ---------------------------------------------------------------------------
template <bool USE_FLAG, bool USE_CV>
__global__ __launch_bounds__(256) void spmm_bf16(
        const u16* __restrict__ x, const int2v* __restrict__ cv,
        const int* __restrict__ col, const float* __restrict__ val,
        const int* __restrict__ ptr, const u32* __restrict__ flag,
        u16* __restrict__ y) {
    int wave = (int)((blockIdx.x * blockDim.x + threadIdx.x) >> 6);
    int lane = threadIdx.x & 63;
    if (wave >= N_NODES) return;
    if (USE_FLAG && flag[wave] == 0) return;
    int e = lane >> 3;          // 0..7
    int d = (lane & 7) << 3;    // 0,8,...,56

    int p0 = ptr[wave];
    int p1 = ptr[wave + 1];

    float8v a0 = {0,0,0,0,0,0,0,0};
    float8v a1 = {0,0,0,0,0,0,0,0};

    int base = p0;
    for (; base + 16 <= p1; base += 16) {          // clean full tiles
        edge_clean<USE_CV>(x, cv, col, val, base + e,     d, a0);
        edge_clean<USE_CV>(x, cv, col, val, base + 8 + e, d, a1);
    }
    if (base < p1) {                               // one predicated tile
        int p1m1 = p1 - 1;
        edge_pred<USE_CV>(x, cv, col, val, base + e,     p1, p1m1, d, a0);
        edge_pred<USE_CV>(x, cv, col, val, base + 8 + e, p1, p1m1, d, a1);
    }

    #pragma unroll
    for (int q = 0; q < 8; ++q) a0[q] += a1[q];

    SLOT_REDUCE(a0);

    if (e == 0) {
        ushort8v o;
        #pragma unroll
        for (int q = 0; q < 8; ++q) o[q] = f2bf(a0[q]);
        __builtin_nontemporal_store(o, (ushort8v*)(y + (size_t)wave * EMB + d));
    }
}

// ---------------------------------------------------------------------------
// Layer-3 SpMM restricted to the 8192 selected rows, fused with output
// accumulation: out[slot] += 0.25 * (A * x)[row(slot)].
// ---------------------------------------------------------------------------
template <bool USE_CV>
__global__ __launch_bounds__(256) void spmm_bf16_sel(
        const u16* __restrict__ x, const int2v* __restrict__ cv,
        const int* __restrict__ col, const float* __restrict__ val,
        const int* __restrict__ ptr, const int* __restrict__ users,
        const int* __restrict__ items, float* __restrict__ out) {
    int slot = (int)((blockIdx.x * blockDim.x + threadIdx.x) >> 6);
    if (slot >= 2 * BATCH) return;
    int lane = threadIdx.x & 63;
    int e = lane >> 3;
    int d = (lane & 7) << 3;

    int row = (slot < BATCH) ? users[slot] : (items[slot - BATCH] + USER_COUNT);
    int p0 = ptr[row];
    int p1 = ptr[row + 1];

    float8v a0 = {0,0,0,0,0,0,0,0};
    float8v a1 = {0,0,0,0,0,0,0,0};

    int base = p0;
    for (; base + 16 <= p1; base += 16) {
        edge_clean<USE_CV>(x, cv, col, val, base + e,     d, a0);
        edge_clean<USE_CV>(x, cv, col, val, base + 8 + e, d, a1);
    }
    if (base < p1) {
        int p1m1 = p1 - 1;
        edge_pred<USE_CV>(x, cv, col, val, base + e,     p1, p1m1, d, a0);
        edge_pred<USE_CV>(x, cv, col, val, base + 8 + e, p1, p1m1, d, a1);
    }

    #pragma unroll
    for (int q = 0; q < 8; ++q) a0[q] += a1[q];

    SLOT_REDUCE(a0);

    if (e == 0) {
        float* o = out + (size_t)slot * EMB + d;
        float4 c0 = *(float4*)o;
        float4 c1 = *(float4*)(o + 4);
        c0.x += 0.25f * a0[0]; c0.y += 0.25f * a0[1];
        c0.z += 0.25f * a0[2]; c0.w += 0.25f * a0[3];
        c1.x += 0.25f * a0[4]; c1.y += 0.25f * a0[5];
        c1.z += 0.25f * a0[6]; c1.w += 0.25f * a0[7];
        *(float4*)o       = c0;
        *(float4*)(o + 4) = c1;
    }
}

// ---------------------------------------------------------------------------
// out = 0.25 * ego[selected]  (exact f32 inputs; first write)
// ---------------------------------------------------------------------------
__global__ void gather_f32(const float* __restrict__ xu,
                           const float* __restrict__ xi,
                           const int* __restrict__ users,
                           const int* __restrict__ items,
                           float* __restrict__ out) {
    int tid = blockIdx.x * blockDim.x + threadIdx.x;
    if (tid >= 2 * BATCH * (EMB / 4)) return;
    int b = tid >> 4;
    int e = (tid & 15) << 2;
    const float* src;
    if (b < BATCH) src = xu + (size_t)users[b] * EMB + e;
    else           src = xi + (size_t)items[b - BATCH] * EMB + e;
    float4 s = *(const float4*)src;
    float4 v = {0.25f * s.x, 0.25f * s.y, 0.25f * s.z, 0.25f * s.w};
    *(float4*)(out + (size_t)b * EMB + e) = v;
}

// ---------------------------------------------------------------------------
// out += 0.25 * h[selected]  (bf16 source)
// ---------------------------------------------------------------------------
__global__ void gather_bf16_add(const u16* __restrict__ h,
                                const int* __restrict__ users,
                                const int* __restrict__ items,
                                float* __restrict__ out) {
    int tid = blockIdx.x * blockDim.x + threadIdx.x;
    if (tid >= 2 * BATCH * (EMB / 4)) return;
    int b = tid >> 4;
    int e = (tid & 15) << 2;
    int row = (b < BATCH) ? users[b] : (items[b - BATCH] + USER_COUNT);
    ushort4 s = *(const ushort4*)(h + (size_t)row * EMB + e);
    float4* o = (float4*)(out + (size_t)b * EMB + e);
    float4 cur = *o;
    cur.x += 0.25f * bf2f(s.x);
    cur.y += 0.25f * bf2f(s.y);
    cur.z += 0.25f * bf2f(s.z);
    cur.w += 0.25f * bf2f(s.w);
    *o = cur;
}

extern "C" void kernel_launch(void* const* d_in, const int* in_sizes, int n_in,
                              void* d_out, int out_size, void* d_ws, size_t ws_size,
                              hipStream_t stream) {
    const float* user_emb = (const float*)d_in[0];
    const float* item_emb = (const float*)d_in[1];
    const int*   adj_row  = (const int*)d_in[2];
    const int*   adj_col  = (const int*)d_in[3];
    const float* adj_val  = (const float*)d_in[4];
    const int*   users    = (const int*)d_in[5];
    const int*   items    = (const int*)d_in[6];
    float*       out      = (float*)d_out;
    const int    nnz      = in_sizes[2];

    char* ws = (char*)d_ws;
    const size_t hbytes = (size_t)N_NODES * EMB * sizeof(u16); // 38.4 MB
    u16* ego16 = (u16*)(ws);
    u16* h1    = (u16*)(ws + hbytes);
    u16* h2    = (u16*)(ws + 2 * hbytes);
    int* ptr   = (int*)(ws + 3 * hbytes);
    u32* flag  = (u32*)(ws + 3 * hbytes + (size_t)(N_NODES + 64) * sizeof(int));
    size_t fixed = 3 * hbytes + 2 * (size_t)(N_NODES + 64) * sizeof(int);
    // cv (8B/edge) only if workspace allows
    bool use_cv = (fixed + (size_t)nnz * 8 + 256) <= ws_size;
    int2v* cv = (int2v*)(ws + ((fixed + 255) & ~(size_t)255));

    // 0) clear needed-flags (ws is NOT re-poisoned between timed replays)
    hipMemsetAsync(flag, 0, (size_t)N_NODES * sizeof(u32), stream);

    // 1) row_ptr
    build_row_ptr<<<(nnz + 255) / 256, 256, 0, stream>>>(adj_row, ptr, nnz);

    // 1b) interleaved col/val records
    if (use_cv)
        build_cv<<<(nnz + 255) / 256, 256, 0, stream>>>(adj_col, adj_val, cv, nnz);

    // 2) ego -> bf16
    {
        const size_t total = (size_t)N_NODES * EMB / 4;
        convert_bf16<<<(unsigned)((total + 255) / 256), 256, 0, stream>>>(
            user_emb, item_emb, ego16);
    }

    // 2b) mark rows whose h2 is consumed
    mark_needed<<<(2 * BATCH + 3) / 4, 256, 0, stream>>>(
        users, items, adj_col, ptr, flag);

    // 3) out = 0.25 * ego[sel]  (exact f32)
    const int gthreads = 2 * BATCH * (EMB / 4);
    gather_f32<<<(gthreads + 255) / 256, 256, 0, stream>>>(
        user_emb, item_emb, users, items, out);

    const int spmm_blocks = (N_NODES + 3) / 4;
    const int sel_blocks  = (2 * BATCH + 3) / 4;

    if (use_cv) {
        spmm_bf16<false, true><<<spmm_blocks, 256, 0, stream>>>(
            ego16, cv, adj_col, adj_val, ptr, nullptr, h1);
        gather_bf16_add<<<(gthreads + 255) / 256, 256, 0, stream>>>(h1, users, items, out);
        spmm_bf16<true, true><<<spmm_blocks, 256, 0, stream>>>(
            h1, cv, adj_col, adj_val, ptr, flag, h2);
        gather_bf16_add<<<(gthreads + 255) / 256, 256, 0, stream>>>(h2, users, items, out);
        spmm_bf16_sel<true><<<sel_blocks, 256, 0, stream>>>(
            h2, cv, adj_col, adj_val, ptr, users, items, out);
    } else {
        spmm_bf16<false, false><<<spmm_blocks, 256, 0, stream>>>(
            ego16, nullptr, adj_col, adj_val, ptr, nullptr, h1);
        gather_bf16_add<<<(gthreads + 255) / 256, 256, 0, stream>>>(h1, users, items, out);
        spmm_bf16<true, false><<<spmm_blocks, 256, 0, stream>>>(
            h1, nullptr, adj_col, adj_val, ptr, flag, h2);
        gather_bf16_add<<<(gthreads + 255) / 256, 256, 0, stream>>>(h2, users, items, out);
        spmm_bf16_sel<false><<<sel_blocks, 256, 0, stream>>>(
            h2, nullptr, adj_col, adj_val, ptr, users, items, out);
    }
}

// Round 9
// 371.333 us; speedup vs baseline: 1.1257x; 1.1257x over previous
//
#include <hip/hip_runtime.h>

#define USER_COUNT 200000
#define ITEM_COUNT 100000
#define N_NODES    300000   // USER_COUNT + ITEM_COUNT
#define EMB        64
#define BATCH      4096

typedef unsigned int   u32;
typedef unsigned short u16;
typedef unsigned char  u8;
typedef float float2v  __attribute__((ext_vector_type(2)));
typedef float float8v  __attribute__((ext_vector_type(8)));
typedef u32   u32x2    __attribute__((ext_vector_type(2)));

// ---------------------------------------------------------------------------
// fp8 (OCP e4m3 on gfx950) pack/unpack via HW converters.
// ---------------------------------------------------------------------------
static __device__ __forceinline__ u32 pk4_fp8(float a, float b, float c, float d) {
    u32 w = 0;
    w = (u32)__builtin_amdgcn_cvt_pk_fp8_f32(a, b, (int)w, false); // low half
    w = (u32)__builtin_amdgcn_cvt_pk_fp8_f32(c, d, (int)w, true);  // high half
    return w;
}
static __device__ __forceinline__ void unpk4_fp8(u32 w, float* o) {
    float2v lo = __builtin_amdgcn_cvt_pk_f32_fp8((int)w, false);
    float2v hi = __builtin_amdgcn_cvt_pk_f32_fp8((int)w, true);
    o[0] = lo.x; o[1] = lo.y; o[2] = hi.x; o[3] = hi.y;
}

// ---------------------------------------------------------------------------
// row_ptr from sorted COO rows. ptr[r] = first i with row[i] >= r.
// ---------------------------------------------------------------------------
__global__ void build_row_ptr(const int* __restrict__ row,
                              int* __restrict__ ptr, int nnz) {
    int i = blockIdx.x * blockDim.x + threadIdx.x;
    if (i >= nnz) return;
    int r  = row[i];
    int rp = (i == 0) ? -1 : row[i - 1];
    for (int rr = rp + 1; rr <= r; ++rr) ptr[rr] = i;
    if (i == nnz - 1) {
        for (int rr = r + 1; rr <= N_NODES; ++rr) ptr[rr] = nnz;
    }
}

// ---------------------------------------------------------------------------
// ego8 = fp8(concat(user_emb, item_emb)); each thread converts 4 elems.
// ---------------------------------------------------------------------------
__global__ void convert_fp8(const float* __restrict__ ue,
                            const float* __restrict__ ie,
                            u32* __restrict__ out8) {
    size_t t = (size_t)blockIdx.x * blockDim.x + threadIdx.x;
    const size_t total = (size_t)N_NODES * EMB / 4;
    if (t >= total) return;
    size_t base = t * 4;
    const size_t ub = (size_t)USER_COUNT * EMB;
    const float* src = (base < ub) ? (ue + base) : (ie + (base - ub));
    float4 v = *(const float4*)src;
    out8[t] = pk4_fp8(v.x, v.y, v.z, v.w);
}

// ---------------------------------------------------------------------------
// Mark nodes whose h2 row is actually consumed.
// ---------------------------------------------------------------------------
__global__ void mark_needed(const int* __restrict__ users,
                            const int* __restrict__ items,
                            const int* __restrict__ col,
                            const int* __restrict__ ptr,
                            u32* __restrict__ flag) {
    int slot = (int)((blockIdx.x * blockDim.x + threadIdx.x) >> 6);
    if (slot >= 2 * BATCH) return;
    int lane = threadIdx.x & 63;
    int row = (slot < BATCH) ? users[slot] : (items[slot - BATCH] + USER_COUNT);
    if (lane == 0) flag[row] = 1;
    int p0 = ptr[row];
    int p1 = ptr[row + 1];
    for (int j = p0 + lane; j < p1; j += 64) flag[col[j]] = 1;
}

// ---------------------------------------------------------------------------
// Edge steps. 8-lane group per edge; lane covers 8 fp8 dims (8 B = u32x2
// gather -> one 64 B cache line per edge).
// ---------------------------------------------------------------------------
static __device__ __forceinline__ void fma_fp8(u32x2 h, float v, float8v& acc) {
    float xf[8];
    unpk4_fp8(h.x, xf);
    unpk4_fp8(h.y, xf + 4);
    #pragma unroll
    for (int q = 0; q < 8; ++q) acc[q] += v * xf[q];
}

static __device__ __forceinline__ void edge_clean(
        const u8* __restrict__ x, const int* __restrict__ col,
        const float* __restrict__ val, int j, int d, float8v& acc) {
    int   c = __builtin_nontemporal_load(col + j);
    float v = __builtin_nontemporal_load(val + j);
    u32x2 h = *(const u32x2*)(x + (size_t)c * EMB + d);
    fma_fp8(h, v, acc);
}

static __device__ __forceinline__ void edge_pred(
        const u8* __restrict__ x, const int* __restrict__ col,
        const float* __restrict__ val, int jj, int p1, int p1m1, int d,
        float8v& acc) {
    int jc = (jj < p1) ? jj : p1m1;
    int   c = __builtin_nontemporal_load(col + jc);
    float v = __builtin_nontemporal_load(val + jc);
    v = (jj < p1) ? v : 0.0f;
    u32x2 h = *(const u32x2*)(x + (size_t)c * EMB + d);
    fma_fp8(h, v, acc);
}

#define SLOT_REDUCE(ACC)                                              \
    _Pragma("unroll")                                                 \
    for (int q = 0; q < 8; ++q) {                                     \
        ACC[q] += __shfl_xor(ACC[q], 8, 64);                          \
        ACC[q] += __shfl_xor(ACC[q], 16, 64);                         \
        ACC[q] += __shfl_xor(ACC[q], 32, 64);                         \
    }

// ---------------------------------------------------------------------------
// Full SpMM (fp8 in / fp8 out): one wave per row.
//   e = lane>>3 : edge slot (8 concurrent edges); d = (lane&7)*8 byte offset.
// Clean main loop + one predicated epilogue tile; wave-uniform trips.
// USE_FLAG: skip rows whose output is never consumed.
// ---------------------------------------------------------------------------
template <bool USE_FLAG>
__global__ __launch_bounds__(256) void spmm_fp8(
        const u8* __restrict__ x, const int* __restrict__ col,
        const float* __restrict__ val, const int* __restrict__ ptr,
        const u32* __restrict__ flag, u8* __restrict__ y) {
    int wave = (int)((blockIdx.x * blockDim.x + threadIdx.x) >> 6);
    int lane = threadIdx.x & 63;
    if (wave >= N_NODES) return;
    if (USE_FLAG && flag[wave] == 0) return;
    int e = lane >> 3;          // 0..7
    int d = (lane & 7) << 3;    // byte offset 0,8,...,56

    int p0 = ptr[wave];
    int p1 = ptr[wave + 1];

    float8v a0 = {0,0,0,0,0,0,0,0};
    float8v a1 = {0,0,0,0,0,0,0,0};

    int base = p0;
    for (; base + 16 <= p1; base += 16) {          // clean full tiles
        edge_clean(x, col, val, base + e,     d, a0);
        edge_clean(x, col, val, base + 8 + e, d, a1);
    }
    if (base < p1) {                               // one predicated tile
        int p1m1 = p1 - 1;
        edge_pred(x, col, val, base + e,     p1, p1m1, d, a0);
        edge_pred(x, col, val, base + 8 + e, p1, p1m1, d, a1);
    }

    #pragma unroll
    for (int q = 0; q < 8; ++q) a0[q] += a1[q];

    SLOT_REDUCE(a0);

    if (e == 0) {
        u32x2 o;
        o.x = pk4_fp8(a0[0], a0[1], a0[2], a0[3]);
        o.y = pk4_fp8(a0[4], a0[5], a0[6], a0[7]);
        __builtin_nontemporal_store(o, (u32x2*)(y + (size_t)wave * EMB + d));
    }
}

// ---------------------------------------------------------------------------
// Layer-3 SpMM restricted to the 8192 selected rows, fused with output
// accumulation: out[slot] += 0.25 * (A * x)[row(slot)].
// ---------------------------------------------------------------------------
__global__ __launch_bounds__(256) void spmm_fp8_sel(
        const u8* __restrict__ x, const int* __restrict__ col,
        const float* __restrict__ val, const int* __restrict__ ptr,
        const int* __restrict__ users, const int* __restrict__ items,
        float* __restrict__ out) {
    int slot = (int)((blockIdx.x * blockDim.x + threadIdx.x) >> 6);
    if (slot >= 2 * BATCH) return;
    int lane = threadIdx.x & 63;
    int e = lane >> 3;
    int d = (lane & 7) << 3;

    int row = (slot < BATCH) ? users[slot] : (items[slot - BATCH] + USER_COUNT);
    int p0 = ptr[row];
    int p1 = ptr[row + 1];

    float8v a0 = {0,0,0,0,0,0,0,0};
    float8v a1 = {0,0,0,0,0,0,0,0};

    int base = p0;
    for (; base + 16 <= p1; base += 16) {
        edge_clean(x, col, val, base + e,     d, a0);
        edge_clean(x, col, val, base + 8 + e, d, a1);
    }
    if (base < p1) {
        int p1m1 = p1 - 1;
        edge_pred(x, col, val, base + e,     p1, p1m1, d, a0);
        edge_pred(x, col, val, base + 8 + e, p1, p1m1, d, a1);
    }

    #pragma unroll
    for (int q = 0; q < 8; ++q) a0[q] += a1[q];

    SLOT_REDUCE(a0);

    if (e == 0) {
        float* o = out + (size_t)slot * EMB + d;   // d doubles as elem offset
        float4 c0 = *(float4*)o;
        float4 c1 = *(float4*)(o + 4);
        c0.x += 0.25f * a0[0]; c0.y += 0.25f * a0[1];
        c0.z += 0.25f * a0[2]; c0.w += 0.25f * a0[3];
        c1.x += 0.25f * a0[4]; c1.y += 0.25f * a0[5];
        c1.z += 0.25f * a0[6]; c1.w += 0.25f * a0[7];
        *(float4*)o       = c0;
        *(float4*)(o + 4) = c1;
    }
}

// ---------------------------------------------------------------------------
// out = 0.25 * ego[selected]  (exact f32 inputs; first write)
// ---------------------------------------------------------------------------
__global__ void gather_f32(const float* __restrict__ xu,
                           const float* __restrict__ xi,
                           const int* __restrict__ users,
                           const int* __restrict__ items,
                           float* __restrict__ out) {
    int tid = blockIdx.x * blockDim.x + threadIdx.x;
    if (tid >= 2 * BATCH * (EMB / 4)) return;
    int b = tid >> 4;
    int e = (tid & 15) << 2;
    const float* src;
    if (b < BATCH) src = xu + (size_t)users[b] * EMB + e;
    else           src = xi + (size_t)items[b - BATCH] * EMB + e;
    float4 s = *(const float4*)src;
    float4 v = {0.25f * s.x, 0.25f * s.y, 0.25f * s.z, 0.25f * s.w};
    *(float4*)(out + (size_t)b * EMB + e) = v;
}

// ---------------------------------------------------------------------------
// out += 0.25 * h[selected]  (fp8 source; thread covers 4 dims)
// ---------------------------------------------------------------------------
__global__ void gather_fp8_add(const u8* __restrict__ h,
                               const int* __restrict__ users,
                               const int* __restrict__ items,
                               float* __restrict__ out) {
    int tid = blockIdx.x * blockDim.x + threadIdx.x;
    if (tid >= 2 * BATCH * (EMB / 4)) return;
    int b = tid >> 4;
    int e = (tid & 15) << 2;
    int row = (b < BATCH) ? users[b] : (items[b - BATCH] + USER_COUNT);
    u32 w = *(const u32*)(h + (size_t)row * EMB + e);
    float xf[4];
    unpk4_fp8(w, xf);
    float4* o = (float4*)(out + (size_t)b * EMB + e);
    float4 cur = *o;
    cur.x += 0.25f * xf[0];
    cur.y += 0.25f * xf[1];
    cur.z += 0.25f * xf[2];
    cur.w += 0.25f * xf[3];
    *o = cur;
}

extern "C" void kernel_launch(void* const* d_in, const int* in_sizes, int n_in,
                              void* d_out, int out_size, void* d_ws, size_t ws_size,
                              hipStream_t stream) {
    const float* user_emb = (const float*)d_in[0];
    const float* item_emb = (const float*)d_in[1];
    const int*   adj_row  = (const int*)d_in[2];
    const int*   adj_col  = (const int*)d_in[3];
    const float* adj_val  = (const float*)d_in[4];
    const int*   users    = (const int*)d_in[5];
    const int*   items    = (const int*)d_in[6];
    float*       out      = (float*)d_out;
    const int    nnz      = in_sizes[2];

    char* ws = (char*)d_ws;
    const size_t hbytes = (size_t)N_NODES * EMB; // 19.2 MB per fp8 table
    u8*  ego8 = (u8*)(ws);
    u8*  h1   = (u8*)(ws + hbytes);
    u8*  h2   = (u8*)(ws + 2 * hbytes);
    int* ptr  = (int*)(ws + 3 * hbytes);
    u32* flag = (u32*)(ws + 3 * hbytes + (size_t)(N_NODES + 64) * sizeof(int));

    // 0) clear needed-flags (ws is NOT re-poisoned between timed replays)
    (void)hipMemsetAsync(flag, 0, (size_t)N_NODES * sizeof(u32), stream);

    // 1) row_ptr
    build_row_ptr<<<(nnz + 255) / 256, 256, 0, stream>>>(adj_row, ptr, nnz);

    // 2) ego -> fp8
    {
        const size_t total = (size_t)N_NODES * EMB / 4;
        convert_fp8<<<(unsigned)((total + 255) / 256), 256, 0, stream>>>(
            user_emb, item_emb, (u32*)ego8);
    }

    // 2b) mark rows whose h2 is consumed
    mark_needed<<<(2 * BATCH + 3) / 4, 256, 0, stream>>>(
        users, items, adj_col, ptr, flag);

    // 3) out = 0.25 * ego[sel]  (exact f32)
    const int gthreads = 2 * BATCH * (EMB / 4);
    gather_f32<<<(gthreads + 255) / 256, 256, 0, stream>>>(
        user_emb, item_emb, users, items, out);

    const int spmm_blocks = (N_NODES + 3) / 4;
    const int sel_blocks  = (2 * BATCH + 3) / 4;

    // 4) h1 = A * ego8 ; out += 0.25*h1[sel]
    spmm_fp8<false><<<spmm_blocks, 256, 0, stream>>>(
        ego8, adj_col, adj_val, ptr, nullptr, h1);
    gather_fp8_add<<<(gthreads + 255) / 256, 256, 0, stream>>>(h1, users, items, out);

    // 5) h2 = A * h1 (only needed rows) ; out += 0.25*h2[sel]
    spmm_fp8<true><<<spmm_blocks, 256, 0, stream>>>(
        h1, adj_col, adj_val, ptr, flag, h2);
    gather_fp8_add<<<(gthreads + 255) / 256, 256, 0, stream>>>(h2, users, items, out);

    // 6) out += 0.25 * (A*h2)[sel]   (layer 3 restricted to 8192 rows)
    spmm_fp8_sel<<<sel_blocks, 256, 0, stream>>>(
        h2, adj_col, adj_val, ptr, users, items, out);
}

// Round 10
// 355.666 us; speedup vs baseline: 1.1753x; 1.0440x over previous
//
#include <hip/hip_runtime.h>

#define USER_COUNT 200000
#define ITEM_COUNT 100000
#define N_NODES    300000   // USER_COUNT + ITEM_COUNT
#define EMB        64
#define BATCH      4096

typedef unsigned int   u32;
typedef unsigned char  u8;
typedef float float2v  __attribute__((ext_vector_type(2)));
typedef float float8v  __attribute__((ext_vector_type(8)));
typedef u32   u32x2    __attribute__((ext_vector_type(2)));

// ---------------------------------------------------------------------------
// fp8 (OCP e4m3 on gfx950) pack/unpack via HW converters.
// ---------------------------------------------------------------------------
static __device__ __forceinline__ u32 pk4_fp8(float a, float b, float c, float d) {
    u32 w = 0;
    w = (u32)__builtin_amdgcn_cvt_pk_fp8_f32(a, b, (int)w, false); // low half
    w = (u32)__builtin_amdgcn_cvt_pk_fp8_f32(c, d, (int)w, true);  // high half
    return w;
}
static __device__ __forceinline__ void unpk4_fp8(u32 w, float* o) {
    float2v lo = __builtin_amdgcn_cvt_pk_f32_fp8((int)w, false);
    float2v hi = __builtin_amdgcn_cvt_pk_f32_fp8((int)w, true);
    o[0] = lo.x; o[1] = lo.y; o[2] = hi.x; o[3] = hi.y;
}

// ---------------------------------------------------------------------------
// row_ptr from sorted COO rows. ptr[r] = first i with row[i] >= r.
// ---------------------------------------------------------------------------
__global__ void build_row_ptr(const int* __restrict__ row,
                              int* __restrict__ ptr, int nnz) {
    int i = blockIdx.x * blockDim.x + threadIdx.x;
    if (i >= nnz) return;
    int r  = row[i];
    int rp = (i == 0) ? -1 : row[i - 1];
    for (int rr = rp + 1; rr <= r; ++rr) ptr[rr] = i;
    if (i == nnz - 1) {
        for (int rr = r + 1; rr <= N_NODES; ++rr) ptr[rr] = nnz;
    }
}

// ---------------------------------------------------------------------------
// ego8 = fp8(concat(user_emb, item_emb)); each thread converts 4 elems.
// ---------------------------------------------------------------------------
__global__ void convert_fp8(const float* __restrict__ ue,
                            const float* __restrict__ ie,
                            u32* __restrict__ out8) {
    size_t t = (size_t)blockIdx.x * blockDim.x + threadIdx.x;
    const size_t total = (size_t)N_NODES * EMB / 4;
    if (t >= total) return;
    size_t base = t * 4;
    const size_t ub = (size_t)USER_COUNT * EMB;
    const float* src = (base < ub) ? (ue + base) : (ie + (base - ub));
    float4 v = *(const float4*)src;
    out8[t] = pk4_fp8(v.x, v.y, v.z, v.w);
}

// ---------------------------------------------------------------------------
// Mark nodes whose h2 row is actually consumed.
// ---------------------------------------------------------------------------
__global__ void mark_needed(const int* __restrict__ users,
                            const int* __restrict__ items,
                            const int* __restrict__ col,
                            const int* __restrict__ ptr,
                            u32* __restrict__ flag) {
    int slot = (int)((blockIdx.x * blockDim.x + threadIdx.x) >> 6);
    if (slot >= 2 * BATCH) return;
    int lane = threadIdx.x & 63;
    int row = (slot < BATCH) ? users[slot] : (items[slot - BATCH] + USER_COUNT);
    if (lane == 0) flag[row] = 1;
    int p0 = ptr[row];
    int p1 = ptr[row + 1];
    for (int j = p0 + lane; j < p1; j += 64) flag[col[j]] = 1;
}

#define SLOT_REDUCE(ACC)                                              \
    _Pragma("unroll")                                                 \
    for (int q = 0; q < 8; ++q) {                                     \
        ACC[q] += __shfl_xor(ACC[q], 8, 64);                          \
        ACC[q] += __shfl_xor(ACC[q], 16, 64);                         \
        ACC[q] += __shfl_xor(ACC[q], 32, 64);                         \
    }

// ---------------------------------------------------------------------------
// Core accumulation over one row segment [p0,p1).
//   e = lane>>3 : edge slot (8 concurrent edges); d = (lane&7)*8 byte offset.
// TILE=32: per iteration, stage 4 col/val pairs and issue 4 row-gathers
// back-to-back (32 independent 64B lines in flight per wave), THEN unpack+FMA.
// Wave-uniform trip count; final tile fully predicated (clamped index,
// masked weight) -> zero divergence. Result: slot-partial sums in a0.
// ---------------------------------------------------------------------------
static __device__ __forceinline__ float8v row_accum(
        const u8* __restrict__ x, const int* __restrict__ col,
        const float* __restrict__ val, int p0, int p1, int e, int d) {
    float8v a0 = {0,0,0,0,0,0,0,0};
    float8v a1 = {0,0,0,0,0,0,0,0};
    float8v a2 = {0,0,0,0,0,0,0,0};
    float8v a3 = {0,0,0,0,0,0,0,0};

    int base = p0;
    for (; base + 32 <= p1; base += 32) {            // clean full tiles
        int j0 = base + e, j1 = j0 + 8, j2 = j0 + 16, j3 = j0 + 24;
        int   c0 = __builtin_nontemporal_load(col + j0);
        int   c1 = __builtin_nontemporal_load(col + j1);
        int   c2 = __builtin_nontemporal_load(col + j2);
        int   c3 = __builtin_nontemporal_load(col + j3);
        float v0 = __builtin_nontemporal_load(val + j0);
        float v1 = __builtin_nontemporal_load(val + j1);
        float v2 = __builtin_nontemporal_load(val + j2);
        float v3 = __builtin_nontemporal_load(val + j3);
        u32x2 h0 = *(const u32x2*)(x + (size_t)c0 * EMB + d);
        u32x2 h1 = *(const u32x2*)(x + (size_t)c1 * EMB + d);
        u32x2 h2 = *(const u32x2*)(x + (size_t)c2 * EMB + d);
        u32x2 h3 = *(const u32x2*)(x + (size_t)c3 * EMB + d);
        float xf[8];
        unpk4_fp8(h0.x, xf); unpk4_fp8(h0.y, xf + 4);
        #pragma unroll
        for (int q = 0; q < 8; ++q) a0[q] += v0 * xf[q];
        unpk4_fp8(h1.x, xf); unpk4_fp8(h1.y, xf + 4);
        #pragma unroll
        for (int q = 0; q < 8; ++q) a1[q] += v1 * xf[q];
        unpk4_fp8(h2.x, xf); unpk4_fp8(h2.y, xf + 4);
        #pragma unroll
        for (int q = 0; q < 8; ++q) a2[q] += v2 * xf[q];
        unpk4_fp8(h3.x, xf); unpk4_fp8(h3.y, xf + 4);
        #pragma unroll
        for (int q = 0; q < 8; ++q) a3[q] += v3 * xf[q];
    }

    if (base < p1) {                                 // one predicated tile
        int p1m1 = p1 - 1;
        int jj0 = base + e, jj1 = jj0 + 8, jj2 = jj0 + 16, jj3 = jj0 + 24;
        int jc0 = (jj0 < p1) ? jj0 : p1m1;
        int jc1 = (jj1 < p1) ? jj1 : p1m1;
        int jc2 = (jj2 < p1) ? jj2 : p1m1;
        int jc3 = (jj3 < p1) ? jj3 : p1m1;
        int   c0 = __builtin_nontemporal_load(col + jc0);
        int   c1 = __builtin_nontemporal_load(col + jc1);
        int   c2 = __builtin_nontemporal_load(col + jc2);
        int   c3 = __builtin_nontemporal_load(col + jc3);
        float v0 = __builtin_nontemporal_load(val + jc0);
        float v1 = __builtin_nontemporal_load(val + jc1);
        float v2 = __builtin_nontemporal_load(val + jc2);
        float v3 = __builtin_nontemporal_load(val + jc3);
        v0 = (jj0 < p1) ? v0 : 0.0f;
        v1 = (jj1 < p1) ? v1 : 0.0f;
        v2 = (jj2 < p1) ? v2 : 0.0f;
        v3 = (jj3 < p1) ? v3 : 0.0f;
        u32x2 h0 = *(const u32x2*)(x + (size_t)c0 * EMB + d);
        u32x2 h1 = *(const u32x2*)(x + (size_t)c1 * EMB + d);
        u32x2 h2 = *(const u32x2*)(x + (size_t)c2 * EMB + d);
        u32x2 h3 = *(const u32x2*)(x + (size_t)c3 * EMB + d);
        float xf[8];
        unpk4_fp8(h0.x, xf); unpk4_fp8(h0.y, xf + 4);
        #pragma unroll
        for (int q = 0; q < 8; ++q) a0[q] += v0 * xf[q];
        unpk4_fp8(h1.x, xf); unpk4_fp8(h1.y, xf + 4);
        #pragma unroll
        for (int q = 0; q < 8; ++q) a1[q] += v1 * xf[q];
        unpk4_fp8(h2.x, xf); unpk4_fp8(h2.y, xf + 4);
        #pragma unroll
        for (int q = 0; q < 8; ++q) a2[q] += v2 * xf[q];
        unpk4_fp8(h3.x, xf); unpk4_fp8(h3.y, xf + 4);
        #pragma unroll
        for (int q = 0; q < 8; ++q) a3[q] += v3 * xf[q];
    }

    #pragma unroll
    for (int q = 0; q < 8; ++q) a0[q] += (a1[q] + a2[q]) + a3[q];
    return a0;
}

// ---------------------------------------------------------------------------
// Full SpMM (fp8 in / fp8 out): one wave per row.
// USE_FLAG: skip rows whose output is never consumed.
// ---------------------------------------------------------------------------
template <bool USE_FLAG>
__global__ __launch_bounds__(256) void spmm_fp8(
        const u8* __restrict__ x, const int* __restrict__ col,
        const float* __restrict__ val, const int* __restrict__ ptr,
        const u32* __restrict__ flag, u8* __restrict__ y) {
    int wave = (int)((blockIdx.x * blockDim.x + threadIdx.x) >> 6);
    int lane = threadIdx.x & 63;
    if (wave >= N_NODES) return;
    if (USE_FLAG && flag[wave] == 0) return;
    int e = lane >> 3;          // 0..7
    int d = (lane & 7) << 3;    // byte offset 0,8,...,56

    int p0 = ptr[wave];
    int p1 = ptr[wave + 1];

    float8v a = row_accum(x, col, val, p0, p1, e, d);
    SLOT_REDUCE(a);

    if (e == 0) {
        u32x2 o;
        o.x = pk4_fp8(a[0], a[1], a[2], a[3]);
        o.y = pk4_fp8(a[4], a[5], a[6], a[7]);
        __builtin_nontemporal_store(o, (u32x2*)(y + (size_t)wave * EMB + d));
    }
}

// ---------------------------------------------------------------------------
// Layer-3 SpMM restricted to the 8192 selected rows, fused with output
// accumulation: out[slot] += 0.25 * (A * x)[row(slot)].
// ---------------------------------------------------------------------------
__global__ __launch_bounds__(256) void spmm_fp8_sel(
        const u8* __restrict__ x, const int* __restrict__ col,
        const float* __restrict__ val, const int* __restrict__ ptr,
        const int* __restrict__ users, const int* __restrict__ items,
        float* __restrict__ out) {
    int slot = (int)((blockIdx.x * blockDim.x + threadIdx.x) >> 6);
    if (slot >= 2 * BATCH) return;
    int lane = threadIdx.x & 63;
    int e = lane >> 3;
    int d = (lane & 7) << 3;

    int row = (slot < BATCH) ? users[slot] : (items[slot - BATCH] + USER_COUNT);
    int p0 = ptr[row];
    int p1 = ptr[row + 1];

    float8v a = row_accum(x, col, val, p0, p1, e, d);
    SLOT_REDUCE(a);

    if (e == 0) {
        float* o = out + (size_t)slot * EMB + d;   // d doubles as elem offset
        float4 c0 = *(float4*)o;
        float4 c1 = *(float4*)(o + 4);
        c0.x += 0.25f * a[0]; c0.y += 0.25f * a[1];
        c0.z += 0.25f * a[2]; c0.w += 0.25f * a[3];
        c1.x += 0.25f * a[4]; c1.y += 0.25f * a[5];
        c1.z += 0.25f * a[6]; c1.w += 0.25f * a[7];
        *(float4*)o       = c0;
        *(float4*)(o + 4) = c1;
    }
}

// ---------------------------------------------------------------------------
// out = 0.25 * ego[selected]  (exact f32 inputs; first write)
// ---------------------------------------------------------------------------
__global__ void gather_f32(const float* __restrict__ xu,
                           const float* __restrict__ xi,
                           const int* __restrict__ users,
                           const int* __restrict__ items,
                           float* __restrict__ out) {
    int tid = blockIdx.x * blockDim.x + threadIdx.x;
    if (tid >= 2 * BATCH * (EMB / 4)) return;
    int b = tid >> 4;
    int e = (tid & 15) << 2;
    const float* src;
    if (b < BATCH) src = xu + (size_t)users[b] * EMB + e;
    else           src = xi + (size_t)items[b - BATCH] * EMB + e;
    float4 s = *(const float4*)src;
    float4 v = {0.25f * s.x, 0.25f * s.y, 0.25f * s.z, 0.25f * s.w};
    *(float4*)(out + (size_t)b * EMB + e) = v;
}

// ---------------------------------------------------------------------------
// out += 0.25 * h[selected]  (fp8 source; thread covers 4 dims)
// ---------------------------------------------------------------------------
__global__ void gather_fp8_add(const u8* __restrict__ h,
                               const int* __restrict__ users,
                               const int* __restrict__ items,
                               float* __restrict__ out) {
    int tid = blockIdx.x * blockDim.x + threadIdx.x;
    if (tid >= 2 * BATCH * (EMB / 4)) return;
    int b = tid >> 4;
    int e = (tid & 15) << 2;
    int row = (b < BATCH) ? users[b] : (items[b - BATCH] + USER_COUNT);
    u32 w = *(const u32*)(h + (size_t)row * EMB + e);
    float xf[4];
    unpk4_fp8(w, xf);
    float4* o = (float4*)(out + (size_t)b * EMB + e);
    float4 cur = *o;
    cur.x += 0.25f * xf[0];
    cur.y += 0.25f * xf[1];
    cur.z += 0.25f * xf[2];
    cur.w += 0.25f * xf[3];
    *o = cur;
}

extern "C" void kernel_launch(void* const* d_in, const int* in_sizes, int n_in,
                              void* d_out, int out_size, void* d_ws, size_t ws_size,
                              hipStream_t stream) {
    const float* user_emb = (const float*)d_in[0];
    const float* item_emb = (const float*)d_in[1];
    const int*   adj_row  = (const int*)d_in[2];
    const int*   adj_col  = (const int*)d_in[3];
    const float* adj_val  = (const float*)d_in[4];
    const int*   users    = (const int*)d_in[5];
    const int*   items    = (const int*)d_in[6];
    float*       out      = (float*)d_out;
    const int    nnz      = in_sizes[2];

    char* ws = (char*)d_ws;
    const size_t hbytes = (size_t)N_NODES * EMB; // 19.2 MB per fp8 table
    u8*  ego8 = (u8*)(ws);
    u8*  h1   = (u8*)(ws + hbytes);
    u8*  h2   = (u8*)(ws + 2 * hbytes);
    int* ptr  = (int*)(ws + 3 * hbytes);
    u32* flag = (u32*)(ws + 3 * hbytes + (size_t)(N_NODES + 64) * sizeof(int));

    // 0) clear needed-flags (ws is NOT re-poisoned between timed replays)
    (void)hipMemsetAsync(flag, 0, (size_t)N_NODES * sizeof(u32), stream);

    // 1) row_ptr
    build_row_ptr<<<(nnz + 255) / 256, 256, 0, stream>>>(adj_row, ptr, nnz);

    // 2) ego -> fp8
    {
        const size_t total = (size_t)N_NODES * EMB / 4;
        convert_fp8<<<(unsigned)((total + 255) / 256), 256, 0, stream>>>(
            user_emb, item_emb, (u32*)ego8);
    }

    // 2b) mark rows whose h2 is consumed
    mark_needed<<<(2 * BATCH + 3) / 4, 256, 0, stream>>>(
        users, items, adj_col, ptr, flag);

    // 3) out = 0.25 * ego[sel]  (exact f32)
    const int gthreads = 2 * BATCH * (EMB / 4);
    gather_f32<<<(gthreads + 255) / 256, 256, 0, stream>>>(
        user_emb, item_emb, users, items, out);

    const int spmm_blocks = (N_NODES + 3) / 4;
    const int sel_blocks  = (2 * BATCH + 3) / 4;

    // 4) h1 = A * ego8 ; out += 0.25*h1[sel]
    spmm_fp8<false><<<spmm_blocks, 256, 0, stream>>>(
        ego8, adj_col, adj_val, ptr, nullptr, h1);
    gather_fp8_add<<<(gthreads + 255) / 256, 256, 0, stream>>>(h1, users, items, out);

    // 5) h2 = A * h1 (only needed rows) ; out += 0.25*h2[sel]
    spmm_fp8<true><<<spmm_blocks, 256, 0, stream>>>(
        h1, adj_col, adj_val, ptr, flag, h2);
    gather_fp8_add<<<(gthreads + 255) / 256, 256, 0, stream>>>(h2, users, items, out);

    // 6) out += 0.25 * (A*h2)[sel]   (layer 3 restricted to 8192 rows)
    spmm_fp8_sel<<<sel_blocks, 256, 0, stream>>>(
        h2, adj_col, adj_val, ptr, users, items, out);
}

// Round 11
// 342.812 us; speedup vs baseline: 1.2194x; 1.0375x over previous
//
#include <hip/hip_runtime.h>

#define USER_COUNT 200000
#define ITEM_COUNT 100000
#define N_NODES    300000   // USER_COUNT + ITEM_COUNT
#define EMB        64
#define BATCH      4096

typedef unsigned int   u32;
typedef unsigned char  u8;
typedef float float2v  __attribute__((ext_vector_type(2)));
typedef float float8v  __attribute__((ext_vector_type(8)));
typedef u32   u32x2    __attribute__((ext_vector_type(2)));

// ---------------------------------------------------------------------------
// fp8 (OCP e4m3 on gfx950) pack/unpack via HW converters.
// ---------------------------------------------------------------------------
static __device__ __forceinline__ u32 pk4_fp8(float a, float b, float c, float d) {
    u32 w = 0;
    w = (u32)__builtin_amdgcn_cvt_pk_fp8_f32(a, b, (int)w, false); // low half
    w = (u32)__builtin_amdgcn_cvt_pk_fp8_f32(c, d, (int)w, true);  // high half
    return w;
}
static __device__ __forceinline__ void unpk4_fp8(u32 w, float* o) {
    float2v lo = __builtin_amdgcn_cvt_pk_f32_fp8((int)w, false);
    float2v hi = __builtin_amdgcn_cvt_pk_f32_fp8((int)w, true);
    o[0] = lo.x; o[1] = lo.y; o[2] = hi.x; o[3] = hi.y;
}

// ---------------------------------------------------------------------------
// Fused prep: (a) row_ptr from sorted COO rows; (b) ego -> fp8 convert.
// Independent ranges, one launch. t < nnz : rowptr ; t < N_NODES*EMB/4 : cvt.
// ---------------------------------------------------------------------------
__global__ void prep_kernel(const int* __restrict__ row,
                            int* __restrict__ ptr,
                            const float* __restrict__ ue,
                            const float* __restrict__ ie,
                            u32* __restrict__ out8, int nnz) {
    size_t t = (size_t)blockIdx.x * blockDim.x + threadIdx.x;

    if (t < (size_t)nnz) {
        int i = (int)t;
        int r  = row[i];
        int rp = (i == 0) ? -1 : row[i - 1];
        for (int rr = rp + 1; rr <= r; ++rr) ptr[rr] = i;
        if (i == nnz - 1) {
            for (int rr = r + 1; rr <= N_NODES; ++rr) ptr[rr] = nnz;
        }
    }

    const size_t total = (size_t)N_NODES * EMB / 4;
    if (t < total) {
        size_t base = t * 4;
        const size_t ub = (size_t)USER_COUNT * EMB;
        const float* src = (base < ub) ? (ue + base) : (ie + (base - ub));
        float4 v = *(const float4*)src;
        out8[t] = pk4_fp8(v.x, v.y, v.z, v.w);
    }
}

// ---------------------------------------------------------------------------
// Mark nodes whose h2 row is actually consumed (sel rows + their neighbors).
// ---------------------------------------------------------------------------
__global__ void mark_needed(const int* __restrict__ users,
                            const int* __restrict__ items,
                            const int* __restrict__ col,
                            const int* __restrict__ ptr,
                            u32* __restrict__ flag) {
    int slot = (int)((blockIdx.x * blockDim.x + threadIdx.x) >> 6);
    if (slot >= 2 * BATCH) return;
    int lane = threadIdx.x & 63;
    int row = (slot < BATCH) ? users[slot] : (items[slot - BATCH] + USER_COUNT);
    if (lane == 0) flag[row] = 1;
    int p0 = ptr[row];
    int p1 = ptr[row + 1];
    for (int j = p0 + lane; j < p1; j += 64) flag[col[j]] = 1;
}

#define SLOT_REDUCE(ACC)                                              \
    _Pragma("unroll")                                                 \
    for (int q = 0; q < 8; ++q) {                                     \
        ACC[q] += __shfl_xor(ACC[q], 8, 64);                          \
        ACC[q] += __shfl_xor(ACC[q], 16, 64);                         \
        ACC[q] += __shfl_xor(ACC[q], 32, 64);                         \
    }

// ---------------------------------------------------------------------------
// Core accumulation over one row segment [p0,p1).
//   e = lane>>3 : edge slot (8 concurrent edges); d = (lane&7)*8 byte offset.
// TILE=32: stage 4 col/val pairs, issue 4 row-gathers back-to-back
// (32 independent 64B lines in flight per wave), then unpack+FMA.
// Wave-uniform trip count; final tile fully predicated -> zero divergence.
// ---------------------------------------------------------------------------
static __device__ __forceinline__ float8v row_accum(
        const u8* __restrict__ x, const int* __restrict__ col,
        const float* __restrict__ val, int p0, int p1, int e, int d) {
    float8v a0 = {0,0,0,0,0,0,0,0};
    float8v a1 = {0,0,0,0,0,0,0,0};
    float8v a2 = {0,0,0,0,0,0,0,0};
    float8v a3 = {0,0,0,0,0,0,0,0};

    int base = p0;
    for (; base + 32 <= p1; base += 32) {            // clean full tiles
        int j0 = base + e, j1 = j0 + 8, j2 = j0 + 16, j3 = j0 + 24;
        int   c0 = __builtin_nontemporal_load(col + j0);
        int   c1 = __builtin_nontemporal_load(col + j1);
        int   c2 = __builtin_nontemporal_load(col + j2);
        int   c3 = __builtin_nontemporal_load(col + j3);
        float v0 = __builtin_nontemporal_load(val + j0);
        float v1 = __builtin_nontemporal_load(val + j1);
        float v2 = __builtin_nontemporal_load(val + j2);
        float v3 = __builtin_nontemporal_load(val + j3);
        u32x2 h0 = *(const u32x2*)(x + (size_t)c0 * EMB + d);
        u32x2 h1 = *(const u32x2*)(x + (size_t)c1 * EMB + d);
        u32x2 h2 = *(const u32x2*)(x + (size_t)c2 * EMB + d);
        u32x2 h3 = *(const u32x2*)(x + (size_t)c3 * EMB + d);
        float xf[8];
        unpk4_fp8(h0.x, xf); unpk4_fp8(h0.y, xf + 4);
        #pragma unroll
        for (int q = 0; q < 8; ++q) a0[q] += v0 * xf[q];
        unpk4_fp8(h1.x, xf); unpk4_fp8(h1.y, xf + 4);
        #pragma unroll
        for (int q = 0; q < 8; ++q) a1[q] += v1 * xf[q];
        unpk4_fp8(h2.x, xf); unpk4_fp8(h2.y, xf + 4);
        #pragma unroll
        for (int q = 0; q < 8; ++q) a2[q] += v2 * xf[q];
        unpk4_fp8(h3.x, xf); unpk4_fp8(h3.y, xf + 4);
        #pragma unroll
        for (int q = 0; q < 8; ++q) a3[q] += v3 * xf[q];
    }

    if (base < p1) {                                 // one predicated tile
        int p1m1 = p1 - 1;
        int jj0 = base + e, jj1 = jj0 + 8, jj2 = jj0 + 16, jj3 = jj0 + 24;
        int jc0 = (jj0 < p1) ? jj0 : p1m1;
        int jc1 = (jj1 < p1) ? jj1 : p1m1;
        int jc2 = (jj2 < p1) ? jj2 : p1m1;
        int jc3 = (jj3 < p1) ? jj3 : p1m1;
        int   c0 = __builtin_nontemporal_load(col + jc0);
        int   c1 = __builtin_nontemporal_load(col + jc1);
        int   c2 = __builtin_nontemporal_load(col + jc2);
        int   c3 = __builtin_nontemporal_load(col + jc3);
        float v0 = __builtin_nontemporal_load(val + jc0);
        float v1 = __builtin_nontemporal_load(val + jc1);
        float v2 = __builtin_nontemporal_load(val + jc2);
        float v3 = __builtin_nontemporal_load(val + jc3);
        v0 = (jj0 < p1) ? v0 : 0.0f;
        v1 = (jj1 < p1) ? v1 : 0.0f;
        v2 = (jj2 < p1) ? v2 : 0.0f;
        v3 = (jj3 < p1) ? v3 : 0.0f;
        u32x2 h0 = *(const u32x2*)(x + (size_t)c0 * EMB + d);
        u32x2 h1 = *(const u32x2*)(x + (size_t)c1 * EMB + d);
        u32x2 h2 = *(const u32x2*)(x + (size_t)c2 * EMB + d);
        u32x2 h3 = *(const u32x2*)(x + (size_t)c3 * EMB + d);
        float xf[8];
        unpk4_fp8(h0.x, xf); unpk4_fp8(h0.y, xf + 4);
        #pragma unroll
        for (int q = 0; q < 8; ++q) a0[q] += v0 * xf[q];
        unpk4_fp8(h1.x, xf); unpk4_fp8(h1.y, xf + 4);
        #pragma unroll
        for (int q = 0; q < 8; ++q) a1[q] += v1 * xf[q];
        unpk4_fp8(h2.x, xf); unpk4_fp8(h2.y, xf + 4);
        #pragma unroll
        for (int q = 0; q < 8; ++q) a2[q] += v2 * xf[q];
        unpk4_fp8(h3.x, xf); unpk4_fp8(h3.y, xf + 4);
        #pragma unroll
        for (int q = 0; q < 8; ++q) a3[q] += v3 * xf[q];
    }

    #pragma unroll
    for (int q = 0; q < 8; ++q) a0[q] += (a1[q] + a2[q]) + a3[q];
    return a0;
}

// ---------------------------------------------------------------------------
// Full SpMM (fp8 in / fp8 out): one wave per row.
// USE_FLAG: skip rows whose output is never consumed.
// ---------------------------------------------------------------------------
template <bool USE_FLAG>
__global__ __launch_bounds__(256) void spmm_fp8(
        const u8* __restrict__ x, const int* __restrict__ col,
        const float* __restrict__ val, const int* __restrict__ ptr,
        const u32* __restrict__ flag, u8* __restrict__ y) {
    int wave = (int)((blockIdx.x * blockDim.x + threadIdx.x) >> 6);
    int lane = threadIdx.x & 63;
    if (wave >= N_NODES) return;
    if (USE_FLAG && flag[wave] == 0) return;
    int e = lane >> 3;          // 0..7
    int d = (lane & 7) << 3;    // byte offset 0,8,...,56

    int p0 = ptr[wave];
    int p1 = ptr[wave + 1];

    float8v a = row_accum(x, col, val, p0, p1, e, d);
    SLOT_REDUCE(a);

    if (e == 0) {
        u32x2 o;
        o.x = pk4_fp8(a[0], a[1], a[2], a[3]);
        o.y = pk4_fp8(a[4], a[5], a[6], a[7]);
        __builtin_nontemporal_store(o, (u32x2*)(y + (size_t)wave * EMB + d));
    }
}

// ---------------------------------------------------------------------------
// Finalize: one wave per output slot.
//   out[slot] = 0.25 * ( ego_f32[row] + h1[row] + h2[row] + (A*h2)[row] )
// Layer-3 sel-SpMM fused with all three gathers and the scale; single pass
// over out, no read-modify-write round trips.
// ---------------------------------------------------------------------------
__global__ __launch_bounds__(256) void finalize(
        const u8* __restrict__ h1, const u8* __restrict__ h2,
        const float* __restrict__ ue, const float* __restrict__ ie,
        const int* __restrict__ col, const float* __restrict__ val,
        const int* __restrict__ ptr, const int* __restrict__ users,
        const int* __restrict__ items, float* __restrict__ out) {
    int slot = (int)((blockIdx.x * blockDim.x + threadIdx.x) >> 6);
    if (slot >= 2 * BATCH) return;
    int lane = threadIdx.x & 63;
    int e = lane >> 3;
    int d = (lane & 7) << 3;

    int row = (slot < BATCH) ? users[slot] : (items[slot - BATCH] + USER_COUNT);
    int p0 = ptr[row];
    int p1 = ptr[row + 1];

    float8v a = row_accum(h2, col, val, p0, p1, e, d);
    SLOT_REDUCE(a);

    if (e == 0) {
        // d = byte offset into fp8 row = element offset into f32 row (8 dims)
        const float* eg = ((row < USER_COUNT) ? (ue + (size_t)row * EMB)
                                              : (ie + (size_t)(row - USER_COUNT) * EMB)) + d;
        u32x2 w1 = *(const u32x2*)(h1 + (size_t)row * EMB + d);
        u32x2 w2 = *(const u32x2*)(h2 + (size_t)row * EMB + d);
        float f1[8], f2[8];
        unpk4_fp8(w1.x, f1); unpk4_fp8(w1.y, f1 + 4);
        unpk4_fp8(w2.x, f2); unpk4_fp8(w2.y, f2 + 4);
        float4 o0, o1;
        o0.x = 0.25f * (eg[0] + f1[0] + f2[0] + a[0]);
        o0.y = 0.25f * (eg[1] + f1[1] + f2[1] + a[1]);
        o0.z = 0.25f * (eg[2] + f1[2] + f2[2] + a[2]);
        o0.w = 0.25f * (eg[3] + f1[3] + f2[3] + a[3]);
        o1.x = 0.25f * (eg[4] + f1[4] + f2[4] + a[4]);
        o1.y = 0.25f * (eg[5] + f1[5] + f2[5] + a[5]);
        o1.z = 0.25f * (eg[6] + f1[6] + f2[6] + a[6]);
        o1.w = 0.25f * (eg[7] + f1[7] + f2[7] + a[7]);
        float* o = out + (size_t)slot * EMB + d;
        *(float4*)o       = o0;
        *(float4*)(o + 4) = o1;
    }
}

extern "C" void kernel_launch(void* const* d_in, const int* in_sizes, int n_in,
                              void* d_out, int out_size, void* d_ws, size_t ws_size,
                              hipStream_t stream) {
    const float* user_emb = (const float*)d_in[0];
    const float* item_emb = (const float*)d_in[1];
    const int*   adj_row  = (const int*)d_in[2];
    const int*   adj_col  = (const int*)d_in[3];
    const float* adj_val  = (const float*)d_in[4];
    const int*   users    = (const int*)d_in[5];
    const int*   items    = (const int*)d_in[6];
    float*       out      = (float*)d_out;
    const int    nnz      = in_sizes[2];

    char* ws = (char*)d_ws;
    const size_t hbytes = (size_t)N_NODES * EMB; // 19.2 MB per fp8 table
    u8*  ego8 = (u8*)(ws);
    u8*  h1   = (u8*)(ws + hbytes);
    u8*  h2   = (u8*)(ws + 2 * hbytes);
    int* ptr  = (int*)(ws + 3 * hbytes);
    u32* flag = (u32*)(ws + 3 * hbytes + (size_t)(N_NODES + 64) * sizeof(int));

    // 0) clear needed-flags (ws is NOT re-poisoned between timed replays)
    (void)hipMemsetAsync(flag, 0, (size_t)N_NODES * sizeof(u32), stream);

    // 1) fused prep: row_ptr + ego->fp8
    prep_kernel<<<(nnz + 255) / 256, 256, 0, stream>>>(
        adj_row, ptr, user_emb, item_emb, (u32*)ego8, nnz);

    // 2) mark rows whose h2 is consumed
    mark_needed<<<(2 * BATCH + 3) / 4, 256, 0, stream>>>(
        users, items, adj_col, ptr, flag);

    const int spmm_blocks = (N_NODES + 3) / 4;
    const int sel_blocks  = (2 * BATCH + 3) / 4;

    // 3) h1 = A * ego8
    spmm_fp8<false><<<spmm_blocks, 256, 0, stream>>>(
        ego8, adj_col, adj_val, ptr, nullptr, h1);

    // 4) h2 = A * h1  (only rows whose output is consumed)
    spmm_fp8<true><<<spmm_blocks, 256, 0, stream>>>(
        h1, adj_col, adj_val, ptr, flag, h2);

    // 5) out = 0.25*(ego[sel] + h1[sel] + h2[sel] + (A*h2)[sel])
    finalize<<<sel_blocks, 256, 0, stream>>>(
        h1, h2, user_emb, item_emb, adj_col, adj_val, ptr, users, items, out);
}